// Round 9
// baseline (931.016 us; speedup 1.0000x reference)
//
#include <hip/hip_runtime.h>
#include <hip/hip_bf16.h>

#define NS 512     // states
#define MS 256     // symbols
#define TB 256     // sequence length
#define NWG 16     // workgroups = batch groups
#define BPG 16     // batches per group
#define NPIN 49    // T cells pinned in VGPRs per wave (of 64)

// workspace byte offsets
#define OFF_EEXP  0u          // f32 [256 sym][512 state]  = 512KB
#define OFF_PEXP  524288u     // f32 [512]
#define OFF_TFRAG 526336u     // bf16 fragment-major [32 st][16 kb][64 lane][8] = 512KB

typedef __attribute__((ext_vector_type(8))) short short8;
typedef __attribute__((ext_vector_type(4))) float f32x4;

__device__ __forceinline__ unsigned short bf_bits(float f) {
    __hip_bfloat16 h = __float2bfloat16(f);
    unsigned short u; __builtin_memcpy(&u, &h, 2); return u;
}

__global__ void k_emission(const float* __restrict__ E, float* __restrict__ expET) {
    int n = blockIdx.x;
    int lane = threadIdx.x;
    const float* row = E + (size_t)n * MS;
    float v[4]; float mx = -1e30f;
#pragma unroll
    for (int j = 0; j < 4; ++j) { v[j] = row[lane + 64 * j]; mx = fmaxf(mx, v[j]); }
#pragma unroll
    for (int off = 1; off < 64; off <<= 1) mx = fmaxf(mx, __shfl_xor(mx, off));
    float s = 0.f;
#pragma unroll
    for (int j = 0; j < 4; ++j) s += __expf(v[j] - mx);
#pragma unroll
    for (int off = 1; off < 64; off <<= 1) s += __shfl_xor(s, off);
    float lse = mx + __logf(s);
#pragma unroll
    for (int j = 0; j < 4; ++j)
        expET[(size_t)(lane + 64 * j) * NS + n] = __expf(v[j] - lse);
}

// T fragments, MFMA-lane-major: cell (st,kb) holds T[state=st*16+li][k=kb*32+hk*8+j]
// at byte ((st*16+kb)<<10) + (hk*16+li)*16 + j*2.  Column-softmax over i (dim 0).
__global__ void k_transition(const float* __restrict__ U, __hip_bfloat16* __restrict__ Tf) {
    int k = blockIdx.x;
    int lane = threadIdx.x;
    float v[8]; float mx = -1e30f;
#pragma unroll
    for (int j = 0; j < 8; ++j) { v[j] = U[(size_t)(lane + 64 * j) * NS + k]; mx = fmaxf(mx, v[j]); }
#pragma unroll
    for (int off = 1; off < 64; off <<= 1) mx = fmaxf(mx, __shfl_xor(mx, off));
    float s = 0.f;
#pragma unroll
    for (int j = 0; j < 8; ++j) s += __expf(v[j] - mx);
#pragma unroll
    for (int off = 1; off < 64; off <<= 1) s += __shfl_xor(s, off);
    float lse = mx + __logf(s);
    int kb = k >> 5, hk = (k >> 3) & 3, jj = k & 7;
#pragma unroll
    for (int j = 0; j < 8; ++j) {
        int i = lane + 64 * j;
        int st = i >> 4, li = i & 15;
        size_t byte = ((size_t)(st * 16 + kb) << 10) + (unsigned)(hk * 16 + li) * 16 + jj * 2;
        *reinterpret_cast<unsigned short*>(reinterpret_cast<char*>(Tf) + byte) =
            bf_bits(__expf(v[j] - lse));
    }
}

__global__ void k_priors(const float* __restrict__ U, float* __restrict__ pexp) {
    int lane = threadIdx.x;
    float v[8]; float mx = -1e30f;
#pragma unroll
    for (int j = 0; j < 8; ++j) { v[j] = U[lane + 64 * j]; mx = fmaxf(mx, v[j]); }
#pragma unroll
    for (int off = 1; off < 64; off <<= 1) mx = fmaxf(mx, __shfl_xor(mx, off));
    float s = 0.f;
#pragma unroll
    for (int j = 0; j < 8; ++j) s += __expf(v[j] - mx);
#pragma unroll
    for (int off = 1; off < 64; off <<= 1) s += __shfl_xor(s, off);
    float lse = mx + __logf(s);
#pragma unroll
    for (int j = 0; j < 8; ++j) pexp[lane + 64 * j] = __expf(v[j] - lse);
}

// 16 WGs x 512 threads (8 waves). WG owns 16 batches + all 512 states.
// Wave w owns output states [w*64,(w+1)*64) = 64 T-cells: 49 pinned in VGPRs
// (asm-kept, 196 regs), 15 in LDS. alpha double-buffered in LDS; deferred
// normalization (rowsum(P_raw(t)) = q(t-1)). ONE barrier per step: qred
// double-buffered by parity; every thread recomputes q redundantly post-bar.
__launch_bounds__(512, 2)
__global__ void k_forward(const int* __restrict__ batch, const float* __restrict__ expET,
                          const __hip_bfloat16* __restrict__ Tf,
                          const float* __restrict__ pexp,
                          float* __restrict__ out) {
    __shared__ __align__(16) char Alds[2][16 * 1024];   // 32KB: A frags per kb
    __shared__ __align__(16) char Tlds[8][15 * 1024];   // 120KB: cells 49..63 per wave
    __shared__ __align__(16) float qred[2][BPG][8];     // 1KB: [par][batch][wave]

    const int tid = threadIdx.x;
    const int lane = tid & 63;
    const int w = tid >> 6;
    const int hi = lane >> 4;
    const int lo = lane & 15;
    const int g = blockIdx.x;
    const int b0 = g * BPG;
    const char* TfC = reinterpret_cast<const char*>(Tf);

    // ---- issue the 49 pinned-cell loads first (L2 latency overlaps prologue) ----
    f32x4 tf[NPIN];
#pragma unroll
    for (int c = 0; c < NPIN; ++c) {
        const int kb = c >> 2, stL = c & 3, st = w * 4 + stL;
        tf[c] = *reinterpret_cast<const f32x4*>(TfC + ((size_t)(st * 16 + kb) << 10) + lane * 16);
    }
#pragma unroll
    for (int c = 0; c < NPIN; ++c)
        asm volatile("" : "+v"(tf[c]));   // opaque: cannot be rematerialized/sunk

    // ---- stage 15 LDS-resident T cells (c = 49..63) ----
#pragma unroll
    for (int c = NPIN; c < 64; ++c) {
        const int kb = c >> 2, stL = c & 3, st = w * 4 + stL;
        short8 v = *reinterpret_cast<const short8*>(TfC + ((size_t)(st * 16 + kb) << 10) + lane * 16);
        *reinterpret_cast<short8*>(&Tlds[w][(c - NPIN) * 1024 + lane * 16]) = v;
    }

    // ---- t = 0: ap0 = Eexp[sym0]*pexp; write A(0) frags; q partials ----
    {
        int symr[4];
#pragma unroll
        for (int r = 0; r < 4; ++r) symr[r] = batch[(size_t)(b0 + hi * 4 + r) * TB];
        float p[4] = {0.f, 0.f, 0.f, 0.f};
#pragma unroll
        for (int stL = 0; stL < 4; ++stL) {
            int s = w * 64 + stL * 16 + lo;
            float pe = pexp[s];
            const int kbp = w * 2 + (stL >> 1);
            const int hip = (stL & 1) * 2 + (lo >> 3);
#pragma unroll
            for (int r = 0; r < 4; ++r) {
                float a = expET[(size_t)symr[r] * NS + s] * pe;
                p[r] += a;
                *reinterpret_cast<unsigned short*>(
                    &Alds[0][kbp * 1024 + (hip * 16 + hi * 4 + r) * 16 + (lo & 7) * 2]) = bf_bits(a);
            }
        }
#pragma unroll
        for (int off = 1; off < 16; off <<= 1)
#pragma unroll
            for (int r = 0; r < 4; ++r) p[r] += __shfl_xor(p[r], off);
        if (lo == 0)
#pragma unroll
            for (int r = 0; r < 4; ++r) qred[0][hi * 4 + r][w] = p[r];
    }
    __syncthreads();

    float nrm = 0.f;   // meaningful in wave 0 (lane L tracks batch L&15)

    // ---- main scan: iteration t consumes A(t-1)/qred(t-1), produces A(t)/qred(t) ----
    for (int t = 1; t < TB; ++t) {
        const int pr = (t - 1) & 1, pw = t & 1;

        // post-bar of step t-1: q(t-1) redundantly per thread; wave0 writes out
        f32x4 qa = *reinterpret_cast<const f32x4*>(&qred[pr][lane & 15][0]);
        f32x4 qb = *reinterpret_cast<const f32x4*>(&qred[pr][lane & 15][4]);
        float qv = ((qa[0] + qa[1]) + (qa[2] + qa[3])) + ((qb[0] + qb[1]) + (qb[2] + qb[3]));
        float qil = 1.0f / qv;
        if (w == 0) {
            nrm += __logf(qv);
            if (lane < 16) out[(size_t)(b0 + lane) * TB + (t - 1)] = nrm;
        }
        float qi[4];
#pragma unroll
        for (int r = 0; r < 4; ++r) qi[r] = __shfl(qil, hi * 4 + r);

        // fac[stL][r] = Eexp[sym_t][s] * qinv(t-1)
        int symr[4];
#pragma unroll
        for (int r = 0; r < 4; ++r) symr[r] = batch[(size_t)(b0 + hi * 4 + r) * TB + t];
        float fac[4][4];
#pragma unroll
        for (int stL = 0; stL < 4; ++stL)
#pragma unroll
            for (int r = 0; r < 4; ++r)
                fac[stL][r] = expET[(size_t)symr[r] * NS + w * 64 + stL * 16 + lo] * qi[r];

        // GEMM: P_raw[b, s] = sum_k A(t-1)[b,k] * T[s,k]
        f32x4 acc[4] = {};
        const char* Ab = &Alds[pr][0];
#pragma unroll
        for (int kb = 0; kb < 16; ++kb) {
            short8 af = *reinterpret_cast<const short8*>(Ab + kb * 1024 + lane * 16);
#pragma unroll
            for (int stL = 0; stL < 4; ++stL) {
                const int c = kb * 4 + stL;
                short8 bf;
                if (c < NPIN) bf = __builtin_bit_cast(short8, tf[c]);
                else bf = *reinterpret_cast<const short8*>(&Tlds[w][(c - NPIN) * 1024 + lane * 16]);
                acc[stL] = __builtin_amdgcn_mfma_f32_16x16x32_bf16(af, bf, acc[stL], 0, 0, 0);
            }
        }

        // epilogue: ap = acc * fac; write A(t) frags; q partials -> qred[pw]
        float p[4] = {0.f, 0.f, 0.f, 0.f};
#pragma unroll
        for (int stL = 0; stL < 4; ++stL) {
            const int kbp = w * 2 + (stL >> 1);
            const int hip = (stL & 1) * 2 + (lo >> 3);
#pragma unroll
            for (int r = 0; r < 4; ++r) {
                float a = acc[stL][r] * fac[stL][r];
                p[r] += a;
                *reinterpret_cast<unsigned short*>(
                    &Alds[pw][kbp * 1024 + (hip * 16 + hi * 4 + r) * 16 + (lo & 7) * 2]) = bf_bits(a);
            }
        }
#pragma unroll
        for (int off = 1; off < 16; off <<= 1)
#pragma unroll
            for (int r = 0; r < 4; ++r) p[r] += __shfl_xor(p[r], off);
        if (lo == 0)
#pragma unroll
            for (int r = 0; r < 4; ++r) qred[pw][hi * 4 + r][w] = p[r];
        __syncthreads();   // the ONLY barrier per step
    }

    // ---- final column t = 255 from qred[1] ----
    if (w == 0) {
        f32x4 qa = *reinterpret_cast<const f32x4*>(&qred[1][lane & 15][0]);
        f32x4 qb = *reinterpret_cast<const f32x4*>(&qred[1][lane & 15][4]);
        float qv = ((qa[0] + qa[1]) + (qa[2] + qa[3])) + ((qb[0] + qb[1]) + (qb[2] + qb[3]));
        nrm += __logf(qv);
        if (lane < 16) out[(size_t)(b0 + lane) * TB + 255] = nrm;
    }
}

extern "C" void kernel_launch(void* const* d_in, const int* in_sizes, int n_in,
                              void* d_out, int out_size, void* d_ws, size_t ws_size,
                              hipStream_t stream) {
    const int* batch = (const int*)d_in[0];
    const float* unE = (const float*)d_in[1];
    const float* unT = (const float*)d_in[2];
    const float* unP = (const float*)d_in[3];
    float* outp = (float*)d_out;

    char* ws = (char*)d_ws;
    float* expET = (float*)(ws + OFF_EEXP);
    float* pexp = (float*)(ws + OFF_PEXP);
    __hip_bfloat16* Tfrag = (__hip_bfloat16*)(ws + OFF_TFRAG);

    k_emission<<<NS, 64, 0, stream>>>(unE, expET);
    k_transition<<<NS, 64, 0, stream>>>(unT, Tfrag);
    k_priors<<<1, 64, 0, stream>>>(unP, pexp);
    k_forward<<<NWG, 512, 0, stream>>>(batch, expET, Tfrag, pexp, outp);
}